// Round 5
// baseline (1693.630 us; speedup 1.0000x reference)
//
#include <hip/hip_runtime.h>
#include <stdint.h>

// BilinearScorer: out[n,r] = sum_{h,k} pred[n,h] U[h,r,k] args[n,k] + bias1[r,:].args[n,:] + bias2[r]
// n=4096, h=k=512, R=64.  137.4 GFLOP fp32-equivalent.
// R10 = launch-count reduction: 4 kernels -> 2.
// R9 post-mortem: cvt_u occupancy fix gained ~0 (non-main 120->119us). Cross-round
// evidence: R6 (3 launches) non-main 89us; R8/R9 (4 launches) 119us; reduce_k's real
// work is 1.7us -> per-launch overhead ~25-30us dominates prep. Fix: fuse cvt_pred
// into cvt_u (prep_fused, branch on blockIdx; also zeroes arrival counters), and
// replace reduce_k with in-main split-K fixup (threadfence + per-(mblk,r) atomic
// arrival counter; 4th arriver sums 4 partials + bias2, writes out). No dispatch-order
// assumption: no spinning, device-scope atomics/fences (G16-safe).
// Main K-loop / staging / swizzle byte-identical to R8/R9 (MfmaUtil 36%, VGPR 68).
// R5: __launch_bounds__(256,3) on main — unified VGPR+AGPR cap fits footprint.

#define HID   512
#define ROLES 64
#define NTOK  4096
#define BM    128
#define BN    128
#define BK    64

typedef __attribute__((ext_vector_type(8))) _Float16 f16x8;  // MFMA A/B operand: 4 VGPRs
typedef __attribute__((ext_vector_type(4))) _Float16 f16x4;
typedef __attribute__((ext_vector_type(4))) float    f32x4;

__device__ __forceinline__ void async16(const void* g, void* l) {
  // global -> LDS direct copy, 16B/lane. LDS dest is wave-uniform base + lane*16;
  // per-lane SOURCE address is free (implements the store-side swizzle).
  __builtin_amdgcn_global_load_lds(
      (const __attribute__((address_space(1))) uint32_t*)g,
      (__attribute__((address_space(3))) uint32_t*)l, 16, 0, 0);
}

// ---- fused prep: blocks [0,2048) transpose U; [2048,4096) convert pred ----
// cvt_u path: U[h][r][k] -> Ut[r][k][h] fp16 via 128h x 64k f32 LDS tile.
// cvt_pred path: fp32 -> fp16 float4-vectorized; block 2048 zeroes cnt[2048].
__global__ __launch_bounds__(256) void prep_fused(
    const float* __restrict__ pred_in, _Float16* __restrict__ predf,
    const float* __restrict__ U, _Float16* __restrict__ ut,
    unsigned int* __restrict__ cnt) {
  __shared__ float tile[128][65];                // pad 65: col-reads 4-way max
  const int bx = blockIdx.x;
  const int t  = threadIdx.x;

  if (bx >= 2048) {                              // ---- cvt_pred path ----
    const int idx = (bx - 2048) * 256 + t;       // 2048 blocks x 256 x float4
    const float4 v = ((const float4*)pred_in)[idx];
    f16x4 o;
    o[0] = (_Float16)v.x; o[1] = (_Float16)v.y;
    o[2] = (_Float16)v.z; o[3] = (_Float16)v.w;
    ((f16x4*)predf)[idx] = o;
    if (bx == 2048)                              // zero split-K arrival counters
      for (int i = t; i < 2048; i += 256) cnt[i] = 0u;
    return;
  }

  // ---- cvt_u path: grid-flattened (kb 8, hb 4, r 64) ----
  const int kb = bx & 7, hb = (bx >> 3) & 3, r = bx >> 5;
  const int h0 = hb * 128, k0 = kb * 64;
  // read: 8 passes x 16 rows; 256B contiguous per row (16 lanes x float4)
  const int rr = t >> 4, c4 = (t & 15) * 4;
#pragma unroll
  for (int pass = 0; pass < 8; pass++) {
    const int row = pass * 16 + rr;
    const float4 v = *(const float4*)(U + ((size_t)(h0 + row) * ROLES + r) * HID + k0 + c4);
    tile[row][c4 + 0] = v.x; tile[row][c4 + 1] = v.y;
    tile[row][c4 + 2] = v.z; tile[row][c4 + 3] = v.w;
  }
  __syncthreads();
  // write: 4 passes x 16 k-rows; 256B contiguous per k-row (16 lanes x uint4)
  const int kr = t >> 4, hc = (t & 15) * 8;
#pragma unroll
  for (int pass = 0; pass < 4; pass++) {
    const int k = pass * 16 + kr;
    alignas(16) _Float16 hbuf[8];
#pragma unroll
    for (int j = 0; j < 8; j++) hbuf[j] = (_Float16)tile[hc + j][k];
    *(uint4*)(ut + ((size_t)r * HID + k0 + k) * HID + h0 + hc) = *(const uint4*)hbuf;
  }
}

// ---- main fused GEMM + split-K fixup --------------------------------------
__global__ __launch_bounds__(256, 3) void bilinear_mfma(
    const _Float16* __restrict__ predf, const _Float16* __restrict__ utf,
    const float* __restrict__ args, const float* __restrict__ bias1,
    const float* __restrict__ bias2, float* __restrict__ part,
    unsigned int* __restrict__ cnt, float* __restrict__ out) {
  __shared__ _Float16 sA[BM * BK];               // 16 KB
  __shared__ _Float16 sB[BN * BK];               // 16 KB
  __shared__ int lastFlag;

  const int nblk = blockIdx.x, mblk = blockIdx.y, r = blockIdx.z;
  const int m0 = mblk * BM, n0 = nblk * BN;
  const int tid  = threadIdx.x;
  const int wave = tid >> 6, lane = tid & 63;
  const int col  = lane & 15, quad = lane >> 4;
  const int wm = (wave & 1) * 64, wn = (wave >> 1) * 64;

  // staging: tile = 128 rows x 64 f16 (128B/row) = 1024 x 16B chunks, 4 calls.
  // XOR swizzle: LDS slot s of row i holds global chunk (s ^ (i&7)); every 8
  // consecutive lanes cover all 8 bank groups (R2/R3-verified: 0 conflicts).
  const int i_loc = tid >> 3;                    // row 0..31 within call (+32/call)
  const int ko    = ((tid & 7) ^ (i_loc & 7)) * 8;
  const size_t offA = (size_t)(m0 + i_loc) * HID + ko;
  const size_t offB = ((size_t)r * HID + n0 + i_loc) * HID + ko;
  const int ldsW = wave * 512;                   // f16 elems (64 chunks/wave/call)

  // reader slots: row&7 == col&7 for all frag rows (wm, 16*mt ≡ 0 mod 8)
  const int slotL8 = (quad ^ (col & 7)) * 8;     // k-chunks 0..3  (k in [0,32))
  const int slotH8 = slotL8 ^ 32;                // k-chunks 4..7  (k in [32,64))
  int rowA[4], rowB[4];
#pragma unroll
  for (int mt = 0; mt < 4; mt++) rowA[mt] = (wm + mt * 16 + col) * BK;
#pragma unroll
  for (int nt = 0; nt < 4; nt++) rowB[nt] = (wn + nt * 16 + col) * BK;

  f32x4 acc[4][4];
#pragma unroll
  for (int a = 0; a < 4; a++)
#pragma unroll
    for (int b = 0; b < 4; b++) acc[a][b] = (f32x4){0.f, 0.f, 0.f, 0.f};

  for (int k0 = 0; k0 < HID; k0 += BK) {
#pragma unroll
    for (int c = 0; c < 4; c++) {
      async16(predf + offA + (size_t)(c * 32) * HID + k0, sA + c * 2048 + ldsW);
      async16(utf   + offB + (size_t)(c * 32) * HID + k0, sB + c * 2048 + ldsW);
    }
    __syncthreads();                             // drains vmcnt (staging done)

    {                                            // phase 0: k in [k0, k0+32)
      f16x8 a[4], b[4];
#pragma unroll
      for (int mt = 0; mt < 4; mt++) a[mt] = *(const f16x8*)(sA + rowA[mt] + slotL8);
#pragma unroll
      for (int nt = 0; nt < 4; nt++) b[nt] = *(const f16x8*)(sB + rowB[nt] + slotL8);
#pragma unroll
      for (int mt = 0; mt < 4; mt++)
#pragma unroll
        for (int nt = 0; nt < 4; nt++)
          acc[mt][nt] = __builtin_amdgcn_mfma_f32_16x16x32_f16(a[mt], b[nt], acc[mt][nt], 0, 0, 0);
    }
    {                                            // phase 1: k in [k0+32, k0+64)
      f16x8 a[4], b[4];
#pragma unroll
      for (int mt = 0; mt < 4; mt++) a[mt] = *(const f16x8*)(sA + rowA[mt] + slotH8);
#pragma unroll
      for (int nt = 0; nt < 4; nt++) b[nt] = *(const f16x8*)(sB + rowB[nt] + slotH8);
#pragma unroll
      for (int mt = 0; mt < 4; mt++)
#pragma unroll
        for (int nt = 0; nt < 4; nt++)
          acc[mt][nt] = __builtin_amdgcn_mfma_f32_16x16x32_f16(a[mt], b[nt], acc[mt][nt], 0, 0, 0);
    }
    __syncthreads();
  }

  // epilogue: sval[mt][reg] = sum over this wave's n-cols of (T + bias1)*args,
  // 16-lane shfl-reduced (valid at col==0). Then cross-wave combine via LDS
  // (waves 0&2 share m-rows 0..63, 1&3 share 64..127) and ONE coalesced float4
  // partial store per (mt) — no atomics on the data path.
  float b1v[4];
#pragma unroll
  for (int nt = 0; nt < 4; nt++)
    b1v[nt] = bias1[r * HID + n0 + wn + nt * 16 + col];

  float sval[4][4];
#pragma unroll
  for (int mt = 0; mt < 4; mt++) {
#pragma unroll
    for (int reg = 0; reg < 4; reg++) {
      const int m = m0 + wm + mt * 16 + quad * 4 + reg;   // C/D row = quad*4+reg (m89)
      const float* arow = args + (size_t)m * HID + n0 + wn + col;
      float s = 0.f;
#pragma unroll
      for (int nt = 0; nt < 4; nt++)
        s += (acc[mt][nt][reg] + b1v[nt]) * arow[nt * 16];
      s += __shfl_xor(s, 1);
      s += __shfl_xor(s, 2);
      s += __shfl_xor(s, 4);
      s += __shfl_xor(s, 8);                     // reduce 16-lane col group
      sval[mt][reg] = s;
    }
  }

  float* red = (float*)sA;                       // 512B scratch (K-loop done with sA)
  if (wave >= 2 && col == 0) {                   // wn=64 waves publish
#pragma unroll
    for (int mt = 0; mt < 4; mt++)
#pragma unroll
      for (int reg = 0; reg < 4; reg++)
        red[wm + mt * 16 + quad * 4 + reg] = sval[mt][reg];
  }
  __syncthreads();
  if (wave < 2 && col == 0) {                    // wn=0 waves combine + store
    float* pbase = part + (((size_t)nblk * ROLES + r) << 12) + m0;  // part[nblk][r][m]
#pragma unroll
    for (int mt = 0; mt < 4; mt++) {
      const int row = wm + mt * 16 + quad * 4;
      float4 v;
      v.x = sval[mt][0] + red[row + 0];
      v.y = sval[mt][1] + red[row + 1];
      v.z = sval[mt][2] + red[row + 2];
      v.w = sval[mt][3] + red[row + 3];
      *(float4*)(pbase + row) = v;
    }
  }

  // split-K fixup: last arriver of the 4 nblk blocks for (mblk, r) finalizes.
  // Release: threadfence after partial stores, before device-scope atomicAdd.
  __threadfence();
  __syncthreads();
  if (tid == 0) {
    const unsigned old = atomicAdd(&cnt[mblk * ROLES + r], 1u);
    lastFlag = (old == 3u);
  }
  __syncthreads();
  if (lastFlag) {
    __threadfence();                             // acquire side
    if (tid < BM) {
      const int m = m0 + tid;
      float v = bias2[r];
#pragma unroll
      for (int nb = 0; nb < 4; nb++)
        v += part[(((size_t)nb * ROLES + r) << 12) + m];
      out[(size_t)m * ROLES + r] = v;
    }
  }
}

// ---- correctness fallback if workspace is too small (slow, pure fp32) -----
__global__ __launch_bounds__(256) void fallback_k(
    const float* __restrict__ pred, const float* __restrict__ args,
    const float* __restrict__ U, const float* __restrict__ b1,
    const float* __restrict__ b2, float* __restrict__ out) {
  const int idx = blockIdx.x * 256 + threadIdx.x;   // 262144
  const int r = idx >> 12;                          // block-uniform role
  const int n = idx & (NTOK - 1);
  const float* arow = args + (size_t)n * HID;
  const float* prow = pred + (size_t)n * HID;
  float acc = 0.f;
  for (int h = 0; h < HID; h++) {
    const float* urow = U + ((size_t)h * ROLES + r) * HID;
    float s = 0.f;
    for (int k = 0; k < HID; k++) s = fmaf(urow[k], arow[k], s);
    acc = fmaf(prow[h], s, acc);
  }
  float sb = 0.f;
  const float* brow = b1 + (size_t)r * HID;
  for (int k = 0; k < HID; k++) sb = fmaf(brow[k], arow[k], sb);
  out[(size_t)n * ROLES + r] = acc + sb + b2[r];
}

extern "C" void kernel_launch(void* const* d_in, const int* in_sizes, int n_in,
                              void* d_out, int out_size, void* d_ws, size_t ws_size,
                              hipStream_t stream) {
  const float* pred = (const float*)d_in[0];
  const float* args = (const float*)d_in[1];
  const float* U    = (const float*)d_in[2];
  const float* b1   = (const float*)d_in[3];
  const float* b2   = (const float*)d_in[4];
  float* out = (float*)d_out;

  const size_t PRED_ELEMS = (size_t)NTOK * HID;         // 2,097,152
  const size_t U_ELEMS    = (size_t)HID * ROLES * HID;  // 16,777,216
  const size_t PART_ELEMS = (size_t)4 * ROLES * NTOK;   // 1,048,576 f32 (4 MiB)
  const size_t CNT_ELEMS  = 2048;                       // (mblk 32) x (r 64)
  const size_t WS_NEEDED  = (PRED_ELEMS + U_ELEMS) * sizeof(_Float16)
                          + PART_ELEMS * sizeof(float)
                          + CNT_ELEMS * sizeof(unsigned int); // ~40 MiB

  if (ws_size < WS_NEEDED) {
    hipLaunchKernelGGL(fallback_k, dim3((NTOK * ROLES) / 256), dim3(256), 0, stream,
                       pred, args, U, b1, b2, out);
    return;
  }

  _Float16* predf = (_Float16*)d_ws;
  _Float16* utf   = predf + PRED_ELEMS;
  float*    partb = (float*)(utf + U_ELEMS);
  unsigned int* cnt = (unsigned int*)(partb + PART_ELEMS);

  hipLaunchKernelGGL(prep_fused, dim3(4096), dim3(256), 0, stream,
                     pred, predf, U, utf, cnt);
  hipLaunchKernelGGL(bilinear_mfma, dim3(HID / BN, NTOK / BM, ROLES), dim3(256), 0, stream,
                     predf, utf, args, b1, b2, partb, cnt, out);
}

// Round 6
// 275.638 us; speedup vs baseline: 6.1444x; 6.1444x over previous
//
#include <hip/hip_runtime.h>
#include <stdint.h>

// BilinearScorer: out[n,r] = sum_{h,k} pred[n,h] U[h,r,k] args[n,k] + bias1[r,:].args[n,:] + bias2[r]
// n=4096, h=k=512, R=64.  137.4 GFLOP fp32-equivalent.
// R11 = revert R10's fence fixup; consolidate launches 4 -> 3.
// R10 post-mortem: per-block device-scope fences (__threadfence on non-coherent
// XCD L2s -> buffer_wbl2/inv) serialize globally: 8192 blocks x 2 ops x ~90ns
// ~= the observed +1.48ms (main 171->1649us, MfmaUtil 3.4%, traffic unchanged).
// LESSON: no per-block agent-scope fences at 4-digit block counts.
// R11: prep_fused = cvt_pred + cvt_u in one kernel (paths byte-identical to R9);
// bilinear_mfma byte-identical to R9 (171us, MfmaUtil 36%, VGPR 68, no fences);
// reduce_k unchanged. Launch-overhead model (~23us/dispatch) predicts 290->~266us.
// R5: __launch_bounds__(256,3) on main — unified VGPR+AGPR cap fits footprint.

#define HID   512
#define ROLES 64
#define NTOK  4096
#define BM    128
#define BN    128
#define BK    64

typedef __attribute__((ext_vector_type(8))) _Float16 f16x8;  // MFMA A/B operand: 4 VGPRs
typedef __attribute__((ext_vector_type(4))) _Float16 f16x4;
typedef __attribute__((ext_vector_type(4))) float    f32x4;

__device__ __forceinline__ void async16(const void* g, void* l) {
  // global -> LDS direct copy, 16B/lane. LDS dest is wave-uniform base + lane*16;
  // per-lane SOURCE address is free (implements the store-side swizzle).
  __builtin_amdgcn_global_load_lds(
      (const __attribute__((address_space(1))) uint32_t*)g,
      (__attribute__((address_space(3))) uint32_t*)l, 16, 0, 0);
}

// ---- fused prep: blocks [0,2048) transpose U; [2048,4096) convert pred ----
// cvt_u path: U[h][r][k] -> Ut[r][k][h] fp16 via 128h x 64k f32 LDS tile.
// cvt_pred path: fp32 -> fp16 float4-vectorized.
__global__ __launch_bounds__(256) void prep_fused(
    const float* __restrict__ pred_in, _Float16* __restrict__ predf,
    const float* __restrict__ U, _Float16* __restrict__ ut) {
  __shared__ float tile[128][65];                // pad 65: col-reads 4-way max
  const int bx = blockIdx.x;
  const int t  = threadIdx.x;

  if (bx >= 2048) {                              // ---- cvt_pred path ----
    const int idx = (bx - 2048) * 256 + t;       // 2048 blocks x 256 x float4
    const float4 v = ((const float4*)pred_in)[idx];
    f16x4 o;
    o[0] = (_Float16)v.x; o[1] = (_Float16)v.y;
    o[2] = (_Float16)v.z; o[3] = (_Float16)v.w;
    ((f16x4*)predf)[idx] = o;
    return;
  }

  // ---- cvt_u path: grid-flattened (kb 8, hb 4, r 64), as R9's dim3(8,4,64) ----
  const int kb = bx & 7, hb = (bx >> 3) & 3, r = bx >> 5;
  const int h0 = hb * 128, k0 = kb * 64;
  // read: 8 passes x 16 rows; 256B contiguous per row (16 lanes x float4)
  const int rr = t >> 4, c4 = (t & 15) * 4;
#pragma unroll
  for (int pass = 0; pass < 8; pass++) {
    const int row = pass * 16 + rr;
    const float4 v = *(const float4*)(U + ((size_t)(h0 + row) * ROLES + r) * HID + k0 + c4);
    tile[row][c4 + 0] = v.x; tile[row][c4 + 1] = v.y;
    tile[row][c4 + 2] = v.z; tile[row][c4 + 3] = v.w;
  }
  __syncthreads();
  // write: 4 passes x 16 k-rows; 256B contiguous per k-row (16 lanes x uint4)
  const int kr = t >> 4, hc = (t & 15) * 8;
#pragma unroll
  for (int pass = 0; pass < 4; pass++) {
    const int k = pass * 16 + kr;
    alignas(16) _Float16 hbuf[8];
#pragma unroll
    for (int j = 0; j < 8; j++) hbuf[j] = (_Float16)tile[hc + j][k];
    *(uint4*)(ut + ((size_t)r * HID + k0 + k) * HID + h0 + hc) = *(const uint4*)hbuf;
  }
}

// ---- main fused GEMM (byte-identical to R9) -------------------------------
__global__ __launch_bounds__(256, 3) void bilinear_mfma(
    const _Float16* __restrict__ predf, const _Float16* __restrict__ utf,
    const float* __restrict__ args, const float* __restrict__ bias1,
    float* __restrict__ part) {
  __shared__ _Float16 sA[BM * BK];               // 16 KB
  __shared__ _Float16 sB[BN * BK];               // 16 KB

  const int nblk = blockIdx.x, mblk = blockIdx.y, r = blockIdx.z;
  const int m0 = mblk * BM, n0 = nblk * BN;
  const int tid  = threadIdx.x;
  const int wave = tid >> 6, lane = tid & 63;
  const int col  = lane & 15, quad = lane >> 4;
  const int wm = (wave & 1) * 64, wn = (wave >> 1) * 64;

  // staging: tile = 128 rows x 64 f16 (128B/row) = 1024 x 16B chunks, 4 calls.
  // XOR swizzle: LDS slot s of row i holds global chunk (s ^ (i&7)); every 8
  // consecutive lanes cover all 8 bank groups (R2/R3-verified: 0 conflicts).
  const int i_loc = tid >> 3;                    // row 0..31 within call (+32/call)
  const int ko    = ((tid & 7) ^ (i_loc & 7)) * 8;
  const size_t offA = (size_t)(m0 + i_loc) * HID + ko;
  const size_t offB = ((size_t)r * HID + n0 + i_loc) * HID + ko;
  const int ldsW = wave * 512;                   // f16 elems (64 chunks/wave/call)

  // reader slots: row&7 == col&7 for all frag rows (wm, 16*mt ≡ 0 mod 8)
  const int slotL8 = (quad ^ (col & 7)) * 8;     // k-chunks 0..3  (k in [0,32))
  const int slotH8 = slotL8 ^ 32;                // k-chunks 4..7  (k in [32,64))
  int rowA[4], rowB[4];
#pragma unroll
  for (int mt = 0; mt < 4; mt++) rowA[mt] = (wm + mt * 16 + col) * BK;
#pragma unroll
  for (int nt = 0; nt < 4; nt++) rowB[nt] = (wn + nt * 16 + col) * BK;

  f32x4 acc[4][4];
#pragma unroll
  for (int a = 0; a < 4; a++)
#pragma unroll
    for (int b = 0; b < 4; b++) acc[a][b] = (f32x4){0.f, 0.f, 0.f, 0.f};

  for (int k0 = 0; k0 < HID; k0 += BK) {
#pragma unroll
    for (int c = 0; c < 4; c++) {
      async16(predf + offA + (size_t)(c * 32) * HID + k0, sA + c * 2048 + ldsW);
      async16(utf   + offB + (size_t)(c * 32) * HID + k0, sB + c * 2048 + ldsW);
    }
    __syncthreads();                             // drains vmcnt (staging done)

    {                                            // phase 0: k in [k0, k0+32)
      f16x8 a[4], b[4];
#pragma unroll
      for (int mt = 0; mt < 4; mt++) a[mt] = *(const f16x8*)(sA + rowA[mt] + slotL8);
#pragma unroll
      for (int nt = 0; nt < 4; nt++) b[nt] = *(const f16x8*)(sB + rowB[nt] + slotL8);
#pragma unroll
      for (int mt = 0; mt < 4; mt++)
#pragma unroll
        for (int nt = 0; nt < 4; nt++)
          acc[mt][nt] = __builtin_amdgcn_mfma_f32_16x16x32_f16(a[mt], b[nt], acc[mt][nt], 0, 0, 0);
    }
    {                                            // phase 1: k in [k0+32, k0+64)
      f16x8 a[4], b[4];
#pragma unroll
      for (int mt = 0; mt < 4; mt++) a[mt] = *(const f16x8*)(sA + rowA[mt] + slotH8);
#pragma unroll
      for (int nt = 0; nt < 4; nt++) b[nt] = *(const f16x8*)(sB + rowB[nt] + slotH8);
#pragma unroll
      for (int mt = 0; mt < 4; mt++)
#pragma unroll
        for (int nt = 0; nt < 4; nt++)
          acc[mt][nt] = __builtin_amdgcn_mfma_f32_16x16x32_f16(a[mt], b[nt], acc[mt][nt], 0, 0, 0);
    }
    __syncthreads();
  }

  // epilogue: sval[mt][reg] = sum over this wave's n-cols of (T + bias1)*args,
  // 16-lane shfl-reduced (valid at col==0). Then cross-wave combine via LDS
  // (waves 0&2 share m-rows 0..63, 1&3 share 64..127) and ONE coalesced float4
  // partial store per (mt) — no atomics.
  float b1v[4];
#pragma unroll
  for (int nt = 0; nt < 4; nt++)
    b1v[nt] = bias1[r * HID + n0 + wn + nt * 16 + col];

  float sval[4][4];
#pragma unroll
  for (int mt = 0; mt < 4; mt++) {
#pragma unroll
    for (int reg = 0; reg < 4; reg++) {
      const int m = m0 + wm + mt * 16 + quad * 4 + reg;   // C/D row = quad*4+reg (m89)
      const float* arow = args + (size_t)m * HID + n0 + wn + col;
      float s = 0.f;
#pragma unroll
      for (int nt = 0; nt < 4; nt++)
        s += (acc[mt][nt][reg] + b1v[nt]) * arow[nt * 16];
      s += __shfl_xor(s, 1);
      s += __shfl_xor(s, 2);
      s += __shfl_xor(s, 4);
      s += __shfl_xor(s, 8);                     // reduce 16-lane col group
      sval[mt][reg] = s;
    }
  }

  float* red = (float*)sA;                       // 512B scratch (K-loop done with sA)
  if (wave >= 2 && col == 0) {                   // wn=64 waves publish
#pragma unroll
    for (int mt = 0; mt < 4; mt++)
#pragma unroll
      for (int reg = 0; reg < 4; reg++)
        red[wm + mt * 16 + quad * 4 + reg] = sval[mt][reg];
  }
  __syncthreads();
  if (wave < 2 && col == 0) {                    // wn=0 waves combine + store
    float* pbase = part + (((size_t)nblk * ROLES + r) << 12) + m0;  // part[nblk][r][m]
#pragma unroll
    for (int mt = 0; mt < 4; mt++) {
      const int row = wm + mt * 16 + quad * 4;
      float4 v;
      v.x = sval[mt][0] + red[row + 0];
      v.y = sval[mt][1] + red[row + 1];
      v.z = sval[mt][2] + red[row + 2];
      v.w = sval[mt][3] + red[row + 3];
      *(float4*)(pbase + row) = v;
    }
  }
}

// ---- reduce: out[m,r] = sum_nb part[nb][r][m] + bias2[r] ------------------
__global__ __launch_bounds__(256) void reduce_k(const float* __restrict__ part,
                                                const float* __restrict__ b2,
                                                float* __restrict__ out) {
  const int idx = blockIdx.x * 256 + threadIdx.x;   // 262144 = NTOK*ROLES
  const int m = idx >> 6, r = idx & (ROLES - 1);
  float v = b2[r];
#pragma unroll
  for (int nb = 0; nb < 4; nb++)
    v += part[(((size_t)nb * ROLES + r) << 12) + m];
  out[idx] = v;                                   // out[m*64+r] == out[idx]
}

// ---- correctness fallback if workspace is too small (slow, pure fp32) -----
__global__ __launch_bounds__(256) void fallback_k(
    const float* __restrict__ pred, const float* __restrict__ args,
    const float* __restrict__ U, const float* __restrict__ b1,
    const float* __restrict__ b2, float* __restrict__ out) {
  const int idx = blockIdx.x * 256 + threadIdx.x;   // 262144
  const int r = idx >> 12;                          // block-uniform role
  const int n = idx & (NTOK - 1);
  const float* arow = args + (size_t)n * HID;
  const float* prow = pred + (size_t)n * HID;
  float acc = 0.f;
  for (int h = 0; h < HID; h++) {
    const float* urow = U + ((size_t)h * ROLES + r) * HID;
    float s = 0.f;
    for (int k = 0; k < HID; k++) s = fmaf(urow[k], arow[k], s);
    acc = fmaf(prow[h], s, acc);
  }
  float sb = 0.f;
  const float* brow = b1 + (size_t)r * HID;
  for (int k = 0; k < HID; k++) sb = fmaf(brow[k], arow[k], sb);
  out[(size_t)n * ROLES + r] = acc + sb + b2[r];
}

extern "C" void kernel_launch(void* const* d_in, const int* in_sizes, int n_in,
                              void* d_out, int out_size, void* d_ws, size_t ws_size,
                              hipStream_t stream) {
  const float* pred = (const float*)d_in[0];
  const float* args = (const float*)d_in[1];
  const float* U    = (const float*)d_in[2];
  const float* b1   = (const float*)d_in[3];
  const float* b2   = (const float*)d_in[4];
  float* out = (float*)d_out;

  const size_t PRED_ELEMS = (size_t)NTOK * HID;         // 2,097,152
  const size_t U_ELEMS    = (size_t)HID * ROLES * HID;  // 16,777,216
  const size_t PART_ELEMS = (size_t)4 * ROLES * NTOK;   // 1,048,576 f32 (4 MiB)
  const size_t WS_NEEDED  = (PRED_ELEMS + U_ELEMS) * sizeof(_Float16)
                          + PART_ELEMS * sizeof(float); // ~40 MiB

  if (ws_size < WS_NEEDED) {
    hipLaunchKernelGGL(fallback_k, dim3((NTOK * ROLES) / 256), dim3(256), 0, stream,
                       pred, args, U, b1, b2, out);
    return;
  }

  _Float16* predf = (_Float16*)d_ws;
  _Float16* utf   = predf + PRED_ELEMS;
  float*    partb = (float*)(utf + U_ELEMS);

  hipLaunchKernelGGL(prep_fused, dim3(4096), dim3(256), 0, stream,
                     pred, predf, U, utf);
  hipLaunchKernelGGL(bilinear_mfma, dim3(HID / BN, NTOK / BM, ROLES), dim3(256), 0, stream,
                     predf, utf, args, b1, partb);
  hipLaunchKernelGGL(reduce_k, dim3((NTOK * ROLES) / 256), dim3(256), 0, stream,
                     partb, b2, out);
}